// Round 2
// baseline (17793.335 us; speedup 1.0000x reference)
//
#include <hip/hip_runtime.h>

typedef unsigned short u16;
typedef unsigned int u32;
typedef short v8s __attribute__((ext_vector_type(8)));
typedef float v4f __attribute__((ext_vector_type(4)));

constexpr int BB = 64;      // batch
constexpr int TT = 800;     // timesteps
constexpr int AUGW = 1120;  // [h0(512) | win(80) | stroke(3) | h1prev(512) | pad(13)]
constexpr int AUG2W = 1024; // [h1(512) | h2prev(512)]
constexpr int NBLK = 184;
constexpr int GRP = 23;     // NBLK/8

constexpr size_t AUGR_OFF  = 1024;
constexpr size_t AUG2R_OFF = AUGR_OFF + (size_t)4 * BB * AUGW * 2;
constexpr size_t WAT_OFF   = AUG2R_OFF + (size_t)4 * BB * AUG2W * 2;
constexpr size_t WS_ZERO   = WAT_OFF + (size_t)32 * 512 * 2;

__device__ __forceinline__ float bf2f(u16 u) { return __uint_as_float(((u32)u) << 16); }
__device__ __forceinline__ u16 f2bf(float f) {
    u32 x = __float_as_uint(f);
    return (u16)((x + 0x7fffu + ((x >> 16) & 1u)) >> 16);
}
__device__ __forceinline__ short f2bfs(float f) { return (short)f2bf(f); }
__device__ __forceinline__ float sigf(float x) { return 1.f / (1.f + __expf(-x)); }
__device__ __forceinline__ float tanhf2(float x) { return 1.f - 2.f / (1.f + __expf(2.f * x)); }

// two-level grid barrier: 8 group counters -> super counter -> generation flag
__device__ __forceinline__ void gbar(u32* ctrl, u32 target) {
    __syncthreads();
    if (threadIdx.x == 0) {
        u32* cnt = ctrl + (blockIdx.x & 7) * 16;
        u32* sup = ctrl + 128;
        u32* gen = ctrl + 144;
        bool released = false;
        u32 old = __hip_atomic_fetch_add(cnt, 1u, __ATOMIC_ACQ_REL, __HIP_MEMORY_SCOPE_AGENT);
        if (old == GRP - 1) {
            __hip_atomic_store(cnt, 0u, __ATOMIC_RELAXED, __HIP_MEMORY_SCOPE_AGENT);
            u32 so = __hip_atomic_fetch_add(sup, 1u, __ATOMIC_ACQ_REL, __HIP_MEMORY_SCOPE_AGENT);
            if (so == 7u) {
                __hip_atomic_store(sup, 0u, __ATOMIC_RELAXED, __HIP_MEMORY_SCOPE_AGENT);
                __hip_atomic_store(gen, target, __ATOMIC_RELEASE, __HIP_MEMORY_SCOPE_AGENT);
                released = true;
            }
        }
        if (!released) {
            while (__hip_atomic_load(gen, __ATOMIC_RELAXED, __HIP_MEMORY_SCOPE_AGENT) < target)
                __builtin_amdgcn_s_sleep(2);
            __threadfence();
        }
    }
    __syncthreads();
}

__global__ void wat_init(const float* __restrict__ Wa, u16* __restrict__ WaT) {
    for (int idx = blockIdx.x * 256 + threadIdx.x; idx < 32 * 512; idx += gridDim.x * 256) {
        const int n = idx >> 9, k = idx & 511;
        WaT[idx] = (n < 30) ? f2bf(Wa[k * 30 + n]) : (u16)0;
    }
}

__global__ __launch_bounds__(256, 1) void hw_main(
    const float* __restrict__ stroke, const float* __restrict__ charseq, const float* __restrict__ kappa0,
    const float* __restrict__ W0, const float* __restrict__ U0, const float* __restrict__ b0,
    const float* __restrict__ W1, const float* __restrict__ U1, const float* __restrict__ b1,
    const float* __restrict__ W2, const float* __restrict__ U2, const float* __restrict__ b2,
    const float* __restrict__ ba, const float* __restrict__ Wm, const float* __restrict__ bm,
    float* __restrict__ out, char* __restrict__ ws)
{
    __shared__ __align__(16) char smem[55296];
    u32* ctrl = (u32*)ws;
    u16* augr  = (u16*)(ws + AUGR_OFF);
    u16* aug2r = (u16*)(ws + AUG2R_OFF);
    const u16* WaT = (const u16*)(ws + WAT_OFF);

    const int blk = blockIdx.x, tid = threadIdx.x;
    const int wave = tid >> 6, lane = tid & 63;
    const int quad = lane >> 4, l15 = lane & 15;

    if (blk < 32) {
        // ---------------- Stage S0: lstm0, step t=i.  WG owns all 64 batches x 16 h-cols.
        const int s = blk;
        float* w0s = (float*)smem;        // 3*64
        float* b0s = (float*)smem + 192;  // 64
        float* zb  = (float*)smem + 256;  // 4*64*17
        if (tid < 192) { int d = tid >> 6, c = tid & 63; int cn = (c >> 4) * 512 + s * 16 + (c & 15);
            w0s[d * 64 + c] = W0[d * 2048 + cn]; }
        if (tid < 64) { int c = tid; int cn = (c >> 4) * 512 + s * 16 + (c & 15); b0s[c] = b0[cn]; }
        v8s bw[16];
        {
            const int cn = (l15 >> 2) * 512 + s * 16 + wave * 4 + (l15 & 3);
            #pragma unroll
            for (int kc = 0; kc < 16; kc++)
                #pragma unroll
                for (int j = 0; j < 8; j++)
                    bw[kc][j] = f2bfs(U0[(kc * 32 + quad * 8 + j) * 2048 + cn]);
        }
        float cst[4] = {0.f, 0.f, 0.f, 0.f};
        float* zw = zb + wave * (64 * 17);
        __syncthreads();
        #pragma unroll 1
        for (int i = 0; i <= TT + 3; i++) {
            if (i < TT) {
                const int t = i;
                const u16* Ap = augr + ((size_t)((t + 3) & 3)) * BB * AUGW;
                v4f a0 = {0.f,0.f,0.f,0.f}, a1 = {0.f,0.f,0.f,0.f}, a2 = {0.f,0.f,0.f,0.f}, a3 = {0.f,0.f,0.f,0.f};
                const int kqo = quad * 8;
                #pragma unroll
                for (int kc = 0; kc < 16; kc++) {
                    const int col = kc * 32 + kqo;
                    v8s x0 = *(const v8s*)(Ap + (0 * 16 + l15) * AUGW + col);
                    v8s x1 = *(const v8s*)(Ap + (1 * 16 + l15) * AUGW + col);
                    v8s x2 = *(const v8s*)(Ap + (2 * 16 + l15) * AUGW + col);
                    v8s x3 = *(const v8s*)(Ap + (3 * 16 + l15) * AUGW + col);
                    a0 = __builtin_amdgcn_mfma_f32_16x16x32_bf16(x0, bw[kc], a0, 0, 0, 0);
                    a1 = __builtin_amdgcn_mfma_f32_16x16x32_bf16(x1, bw[kc], a1, 0, 0, 0);
                    a2 = __builtin_amdgcn_mfma_f32_16x16x32_bf16(x2, bw[kc], a2, 0, 0, 0);
                    a3 = __builtin_amdgcn_mfma_f32_16x16x32_bf16(x3, bw[kc], a3, 0, 0, 0);
                }
                #pragma unroll
                for (int r = 0; r < 4; r++) {
                    zw[(0 * 16 + quad * 4 + r) * 17 + l15] = a0[r];
                    zw[(1 * 16 + quad * 4 + r) * 17 + l15] = a1[r];
                    zw[(2 * 16 + quad * 4 + r) * 17 + l15] = a2[r];
                    zw[(3 * 16 + quad * 4 + r) * 17 + l15] = a3[r];
                }
                __syncthreads();
                u16* hdst = augr + ((size_t)(t & 3)) * BB * AUGW;
                #pragma unroll
                for (int r = 0; r < 4; r++) {
                    const int p = tid + 256 * r;
                    const int b = p & 63, j = p >> 6;
                    const float xx0 = stroke[(b * TT + t) * 3 + 0];
                    const float xx1 = stroke[(b * TT + t) * 3 + 1];
                    const float xx2 = stroke[(b * TT + t) * 3 + 2];
                    float z[4];
                    #pragma unroll
                    for (int g = 0; g < 4; g++) {
                        const int c = g * 16 + j;
                        z[g] = zb[(j >> 2) * (64 * 17) + b * 17 + (g * 4 + (j & 3))]
                             + b0s[c] + xx0 * w0s[c] + xx1 * w0s[64 + c] + xx2 * w0s[128 + c];
                    }
                    const float cc = sigf(z[1]) * cst[r] + sigf(z[0]) * tanhf2(z[2]);
                    cst[r] = cc;
                    hdst[b * AUGW + s * 16 + j] = f2bf(sigf(z[3]) * tanhf2(cc));
                }
            }
            if (i < TT + 3) gbar(ctrl, (u32)(i + 1));
        }
    } else if (blk < 96) {
        // ---------------- Stage S1: lstm1, step t1=i-2.  32 batches x 16 h-cols per WG.
        const int q = blk - 32, mg = q >> 5, cs = q & 31;
        float* b1s = (float*)smem;
        float* zb  = (float*)smem + 64;   // 4*32*17
        if (tid < 64) { int c = tid; int cn = (c >> 4) * 512 + cs * 16 + (c & 15); b1s[c] = b1[cn]; }
        v8s bw[35];
        {
            const int cn = (l15 >> 2) * 512 + cs * 16 + wave * 4 + (l15 & 3);
            #pragma unroll
            for (int kc = 0; kc < 35; kc++)
                #pragma unroll
                for (int j = 0; j < 8; j++) {
                    const int k = kc * 32 + quad * 8 + j;
                    short v = 0;
                    if (k < 595) v = f2bfs(W1[k * 2048 + cn]);
                    else if (k < 1107) v = f2bfs(U1[(k - 595) * 2048 + cn]);
                    bw[kc][j] = v;
                }
        }
        float cst[2] = {0.f, 0.f};
        float* zw = zb + wave * (32 * 17);
        __syncthreads();
        #pragma unroll 1
        for (int i = 0; i <= TT + 3; i++) {
            if (i >= 2 && i <= TT + 1) {
                const int t1 = i - 2;
                const u16* Ap = augr + ((size_t)(t1 & 3)) * BB * AUGW + (size_t)mg * 32 * AUGW;
                v4f a0 = {0.f,0.f,0.f,0.f}, a1 = {0.f,0.f,0.f,0.f};
                const int kqo = quad * 8;
                #pragma unroll
                for (int kc = 0; kc < 35; kc++) {
                    const int col = kc * 32 + kqo;
                    v8s x0 = *(const v8s*)(Ap + l15 * AUGW + col);
                    v8s x1 = *(const v8s*)(Ap + (16 + l15) * AUGW + col);
                    a0 = __builtin_amdgcn_mfma_f32_16x16x32_bf16(x0, bw[kc], a0, 0, 0, 0);
                    a1 = __builtin_amdgcn_mfma_f32_16x16x32_bf16(x1, bw[kc], a1, 0, 0, 0);
                }
                #pragma unroll
                for (int r = 0; r < 4; r++) {
                    zw[(quad * 4 + r) * 17 + l15] = a0[r];
                    zw[(16 + quad * 4 + r) * 17 + l15] = a1[r];
                }
                __syncthreads();
                u16* h1a = augr + ((size_t)((t1 + 1) & 3)) * BB * AUGW;
                u16* h1b = aug2r + ((size_t)(t1 & 3)) * BB * AUG2W;
                #pragma unroll
                for (int r = 0; r < 2; r++) {
                    const int p = tid + 256 * r;
                    const int bl = p & 31, j = p >> 5;
                    const int b = mg * 32 + bl;
                    float z[4];
                    #pragma unroll
                    for (int g = 0; g < 4; g++)
                        z[g] = zb[(j >> 2) * (32 * 17) + bl * 17 + (g * 4 + (j & 3))] + b1s[g * 16 + j];
                    const float cc = sigf(z[1]) * cst[r] + sigf(z[0]) * tanhf2(z[2]);
                    cst[r] = cc;
                    const u16 hv = f2bf(sigf(z[3]) * tanhf2(cc));
                    const int hc = cs * 16 + j;
                    h1a[b * AUGW + 595 + hc] = hv;
                    h1b[b * AUG2W + hc] = hv;
                }
            }
            if (i < TT + 3) gbar(ctrl, (u32)(i + 1));
        }
    } else if (blk < 160) {
        // ---------------- Stage S2: lstm2, step t2=i-3.  32 batches x 16 h-cols per WG.
        const int q = blk - 96, mg = q >> 5, cs = q & 31;
        float* b2s = (float*)smem;
        float* zb  = (float*)smem + 64;
        if (tid < 64) { int c = tid; int cn = (c >> 4) * 512 + cs * 16 + (c & 15); b2s[c] = b2[cn]; }
        v8s bw[32];
        {
            const int cn = (l15 >> 2) * 512 + cs * 16 + wave * 4 + (l15 & 3);
            #pragma unroll
            for (int kc = 0; kc < 32; kc++)
                #pragma unroll
                for (int j = 0; j < 8; j++) {
                    const int k = kc * 32 + quad * 8 + j;
                    bw[kc][j] = (k < 512) ? f2bfs(W2[k * 2048 + cn]) : f2bfs(U2[(k - 512) * 2048 + cn]);
                }
        }
        float cst[2] = {0.f, 0.f};
        float* zw = zb + wave * (32 * 17);
        __syncthreads();
        #pragma unroll 1
        for (int i = 0; i <= TT + 3; i++) {
            if (i >= 3 && i <= TT + 2) {
                const int t2 = i - 3;
                const u16* Ap = aug2r + ((size_t)(t2 & 3)) * BB * AUG2W + (size_t)mg * 32 * AUG2W;
                v4f a0 = {0.f,0.f,0.f,0.f}, a1 = {0.f,0.f,0.f,0.f};
                const int kqo = quad * 8;
                #pragma unroll
                for (int kc = 0; kc < 32; kc++) {
                    const int col = kc * 32 + kqo;
                    v8s x0 = *(const v8s*)(Ap + l15 * AUG2W + col);
                    v8s x1 = *(const v8s*)(Ap + (16 + l15) * AUG2W + col);
                    a0 = __builtin_amdgcn_mfma_f32_16x16x32_bf16(x0, bw[kc], a0, 0, 0, 0);
                    a1 = __builtin_amdgcn_mfma_f32_16x16x32_bf16(x1, bw[kc], a1, 0, 0, 0);
                }
                #pragma unroll
                for (int r = 0; r < 4; r++) {
                    zw[(quad * 4 + r) * 17 + l15] = a0[r];
                    zw[(16 + quad * 4 + r) * 17 + l15] = a1[r];
                }
                __syncthreads();
                u16* h2d = aug2r + ((size_t)((t2 + 1) & 3)) * BB * AUG2W;
                #pragma unroll
                for (int r = 0; r < 2; r++) {
                    const int p = tid + 256 * r;
                    const int bl = p & 31, j = p >> 5;
                    const int b = mg * 32 + bl;
                    float z[4];
                    #pragma unroll
                    for (int g = 0; g < 4; g++)
                        z[g] = zb[(j >> 2) * (32 * 17) + bl * 17 + (g * 4 + (j & 3))] + b2s[g * 16 + j];
                    const float cc = sigf(z[1]) * cst[r] + sigf(z[0]) * tanhf2(z[2]);
                    cst[r] = cc;
                    h2d[b * AUG2W + 512 + cs * 16 + j] = f2bf(sigf(z[3]) * tanhf2(cc));
                }
            }
            if (i < TT + 3) gbar(ctrl, (u32)(i + 1));
        }
    } else if (blk < 176) {
        // ---------------- Stage SA: attention window, step ta=i-1. One batch per wave.
        const int a = blk - 160;
        const int b = a * 4 + wave;
        u16* csb = (u16*)smem;                   // 4*6400 u16
        float* phis = (float*)(smem + 51200);    // 4*80 floats
        #pragma unroll 1
        for (int r = 0; r < 100; r++) { const int idx = r * 64 + lane; csb[wave * 6400 + idx] = f2bf(charseq[b * 6400 + idx]); }
        float kap = (lane < 10) ? kappa0[b * 10 + lane] : 0.f;
        const float baf = (lane < 30) ? ba[lane] : 0.f;
        const int nn = lane & 31;
        const int k0 = (lane >> 5) * 256;
        const u16* wrow = WaT + nn * 512 + k0;
        __syncthreads();
        #pragma unroll 1
        for (int i = 0; i <= TT + 3; i++) {
            if (i >= 1 && i <= TT) {
                const int ta = i - 1;
                const u16* h0p = augr + ((size_t)(ta & 3)) * BB * AUGW + b * AUGW;
                float acc = 0.f;
                #pragma unroll
                for (int kk = 0; kk < 32; kk++) {
                    v8s hv = *(const v8s*)(h0p + k0 + kk * 8);
                    v8s wv = *(const v8s*)(wrow + kk * 8);
                    #pragma unroll
                    for (int e = 0; e < 8; e++) acc += bf2f((u16)hv[e]) * bf2f((u16)wv[e]);
                }
                acc += __shfl_xor(acc, 32);
                const float abk = __expf(acc + baf);
                const float kofv = __shfl(abk, 20 + (lane < 10 ? lane : 0));
                if (lane < 10) kap += kofv;
                const float u1f = (float)lane, u2f = (float)(64 + lane);
                float p1 = 0.f, p2 = 0.f;
                #pragma unroll
                for (int kk = 0; kk < 10; kk++) {
                    const float al = __shfl(abk, kk);
                    const float be = __shfl(abk, 10 + kk);
                    const float kp = __shfl(kap, kk);
                    const float d1 = kp - u1f, d2 = kp - u2f;
                    p1 += al * __expf(-be * d1 * d1);
                    p2 += al * __expf(-be * d2 * d2);
                }
                phis[wave * 80 + lane] = p1;
                if (lane < 16) phis[wave * 80 + 64 + lane] = p2;
                __syncthreads();
                float w1 = 0.f, w2 = 0.f;
                const int c2 = 64 + (lane & 15);
                #pragma unroll 1
                for (int u = 0; u < 80; u++) {
                    const float pv = phis[wave * 80 + u];
                    w1 += pv * bf2f(csb[wave * 6400 + u * 80 + lane]);
                    w2 += pv * bf2f(csb[wave * 6400 + u * 80 + c2]);
                }
                u16* dst = augr + ((size_t)(ta & 3)) * BB * AUGW + b * AUGW + 512;
                dst[lane] = f2bf(w1);
                if (lane < 16) dst[64 + lane] = f2bf(w2);
                if (lane < 3) dst[80 + lane] = f2bf(stroke[(b * TT + ta) * 3 + lane]);
            }
            if (i < TT + 3) gbar(ctrl, (u32)(i + 1));
        }
    } else if (blk < 178) {
        // ---------------- Stage SM: MDN head, step tm=i-4. WG covers 64 batches x 64 N-cols.
        const int wgN = blk - 176;
        float* zb = (float*)smem; // 64*65
        v8s bw[16];
        {
            const int n = wgN * 64 + wave * 16 + l15;
            #pragma unroll
            for (int kc = 0; kc < 16; kc++)
                #pragma unroll
                for (int j = 0; j < 8; j++) {
                    const int k = kc * 32 + quad * 8 + j;
                    bw[kc][j] = (n < 121) ? f2bfs(Wm[k * 121 + n]) : (short)0;
                }
        }
        #pragma unroll 1
        for (int i = 0; i <= TT + 3; i++) {
            if (i >= 4) {
                const int tm = i - 4;
                const u16* Ap = aug2r + ((size_t)((tm + 1) & 3)) * BB * AUG2W + 512;
                v4f a0 = {0.f,0.f,0.f,0.f}, a1 = {0.f,0.f,0.f,0.f}, a2 = {0.f,0.f,0.f,0.f}, a3 = {0.f,0.f,0.f,0.f};
                const int kqo = quad * 8;
                #pragma unroll
                for (int kc = 0; kc < 16; kc++) {
                    const int col = kc * 32 + kqo;
                    v8s x0 = *(const v8s*)(Ap + (0 * 16 + l15) * AUG2W + col);
                    v8s x1 = *(const v8s*)(Ap + (1 * 16 + l15) * AUG2W + col);
                    v8s x2 = *(const v8s*)(Ap + (2 * 16 + l15) * AUG2W + col);
                    v8s x3 = *(const v8s*)(Ap + (3 * 16 + l15) * AUG2W + col);
                    a0 = __builtin_amdgcn_mfma_f32_16x16x32_bf16(x0, bw[kc], a0, 0, 0, 0);
                    a1 = __builtin_amdgcn_mfma_f32_16x16x32_bf16(x1, bw[kc], a1, 0, 0, 0);
                    a2 = __builtin_amdgcn_mfma_f32_16x16x32_bf16(x2, bw[kc], a2, 0, 0, 0);
                    a3 = __builtin_amdgcn_mfma_f32_16x16x32_bf16(x3, bw[kc], a3, 0, 0, 0);
                }
                #pragma unroll
                for (int r = 0; r < 4; r++) {
                    zb[(0 * 16 + quad * 4 + r) * 65 + wave * 16 + l15] = a0[r];
                    zb[(1 * 16 + quad * 4 + r) * 65 + wave * 16 + l15] = a1[r];
                    zb[(2 * 16 + quad * 4 + r) * 65 + wave * 16 + l15] = a2[r];
                    zb[(3 * 16 + quad * 4 + r) * 65 + wave * 16 + l15] = a3[r];
                }
                __syncthreads();
                if (tid < 64) {
                    const int b = tid;
                    float* zr = zb + b * 65;
                    float* orow = out + ((size_t)(b * TT + tm)) * 121;
                    if (wgN == 0) {
                        #pragma unroll 1
                        for (int nl = 0; nl < 64; nl++) zr[nl] += bm[nl];
                        float mx = -1e30f;
                        #pragma unroll 1
                        for (int nl = 1; nl <= 20; nl++) mx = fmaxf(mx, zr[nl]);
                        float ss = 0.f;
                        #pragma unroll 1
                        for (int nl = 1; nl <= 20; nl++) { const float e = __expf(zr[nl] - mx); zr[nl] = e; ss += e; }
                        const float inv = 1.f / ss;
                        orow[0] = sigf(-zr[0]);
                        #pragma unroll 1
                        for (int nl = 1; nl <= 20; nl++) orow[nl] = zr[nl] * inv;
                        #pragma unroll 1
                        for (int nl = 21; nl <= 60; nl++) orow[nl] = zr[nl];
                        #pragma unroll 1
                        for (int nl = 61; nl < 64; nl++) orow[nl] = __expf(zr[nl]);
                    } else {
                        #pragma unroll 1
                        for (int nl = 0; nl < 57; nl++) {
                            const int n = 64 + nl;
                            const float z = zr[nl] + bm[n];
                            orow[n] = (n <= 100) ? __expf(z) : tanhf2(z);
                        }
                    }
                }
            }
            if (i < TT + 3) gbar(ctrl, (u32)(i + 1));
        }
    } else {
        // ---------------- idle blocks: participate in barriers only
        #pragma unroll 1
        for (int i = 0; i <= TT + 3; i++)
            if (i < TT + 3) gbar(ctrl, (u32)(i + 1));
    }
}

extern "C" void kernel_launch(void* const* d_in, const int* in_sizes, int n_in,
                              void* d_out, int out_size, void* d_ws, size_t ws_size,
                              hipStream_t stream) {
    const float* stroke  = (const float*)d_in[0];
    const float* charseq = (const float*)d_in[1];
    const float* kappa0  = (const float*)d_in[2];
    const float* W0 = (const float*)d_in[3];
    const float* U0 = (const float*)d_in[4];
    const float* b0 = (const float*)d_in[5];
    const float* W1 = (const float*)d_in[6];
    const float* U1 = (const float*)d_in[7];
    const float* b1 = (const float*)d_in[8];
    const float* W2 = (const float*)d_in[9];
    const float* U2 = (const float*)d_in[10];
    const float* b2 = (const float*)d_in[11];
    const float* Wa = (const float*)d_in[12];
    const float* ba = (const float*)d_in[13];
    const float* Wm = (const float*)d_in[14];
    const float* bm = (const float*)d_in[15];
    char* ws = (char*)d_ws;

    hipMemsetAsync(d_ws, 0, WS_ZERO, stream);
    wat_init<<<8, 256, 0, stream>>>(Wa, (u16*)(ws + WAT_OFF));
    hw_main<<<NBLK, 256, 0, stream>>>(stroke, charseq, kappa0, W0, U0, b0,
                                      W1, U1, b1, W2, U2, b2, ba, Wm, bm,
                                      (float*)d_out, ws);
}

// Round 3
// 16832.698 us; speedup vs baseline: 1.0571x; 1.0571x over previous
//
#include <hip/hip_runtime.h>

typedef unsigned short u16;
typedef unsigned int u32;
typedef unsigned long long u64;
typedef short v8s __attribute__((ext_vector_type(8)));
typedef float v4f __attribute__((ext_vector_type(4)));

constexpr int BB = 64;      // batch
constexpr int TT = 800;     // timesteps
constexpr int AUGW = 1120;  // [h0(512) | win(80) | stroke(3) | zero-pad(1) | h1prev(596..1107) | pad]
constexpr int AUG2W = 1024; // [h1(512) | h2prev(512)]
constexpr int NBLK = 184;
constexpr int GRP = 23;     // NBLK/8

constexpr size_t AUGR_OFF  = 1024;
constexpr size_t AUG2R_OFF = AUGR_OFF + (size_t)4 * BB * AUGW * 2;
constexpr size_t WAT_OFF   = AUG2R_OFF + (size_t)4 * BB * AUG2W * 2;
constexpr size_t WS_ZERO   = WAT_OFF + (size_t)32 * 512 * 2;

__device__ __forceinline__ float bf2f(u16 u) { return __uint_as_float(((u32)u) << 16); }
__device__ __forceinline__ u16 f2bf(float f) {
    u32 x = __float_as_uint(f);
    return (u16)((x + 0x7fffu + ((x >> 16) & 1u)) >> 16);
}
__device__ __forceinline__ short f2bfs(float f) { return (short)f2bf(f); }
__device__ __forceinline__ float sigf(float x) { return 1.f / (1.f + __expf(-x)); }
__device__ __forceinline__ float tanhf2(float x) { return 1.f - 2.f / (1.f + __expf(2.f * x)); }

// agent-coherent (sc1) data movement: relaxed atomics -> plain global ops with sc1,
// no buffer_wbl2 / buffer_inv cache maintenance.
union Q2 { u64 q[2]; v8s v; };
__device__ __forceinline__ v8s ldv8(const u16* p) {
    Q2 u;
    u.q[0] = __hip_atomic_load((const u64*)p,       __ATOMIC_RELAXED, __HIP_MEMORY_SCOPE_AGENT);
    u.q[1] = __hip_atomic_load((const u64*)(p + 4), __ATOMIC_RELAXED, __HIP_MEMORY_SCOPE_AGENT);
    return u.v;
}
__device__ __forceinline__ void st8(u16* p, u16 a, u16 b, u16 c, u16 d) {
    u64 q = (u64)a | ((u64)b << 16) | ((u64)c << 32) | ((u64)d << 48);
    __hip_atomic_store((u64*)p, q, __ATOMIC_RELAXED, __HIP_MEMORY_SCOPE_AGENT);
}
__device__ __forceinline__ void st4(u16* p, u16 a, u16 b) {
    u32 q = (u32)a | ((u32)b << 16);
    __hip_atomic_store((u32*)p, q, __ATOMIC_RELAXED, __HIP_MEMORY_SCOPE_AGENT);
}

// two-level grid barrier, all-relaxed, monotone counters (no resets -> no ordering hazard)
__device__ __forceinline__ void gbar(u32* ctrl, u32 target) {
    __syncthreads();
    if (threadIdx.x == 0) {
        u32* cnt = ctrl + (blockIdx.x & 7) * 16;
        u32* sup = ctrl + 128;
        u32* gen = ctrl + 144;
        bool released = false;
        u32 old = __hip_atomic_fetch_add(cnt, 1u, __ATOMIC_RELAXED, __HIP_MEMORY_SCOPE_AGENT);
        if (old == target * GRP - 1) {
            u32 so = __hip_atomic_fetch_add(sup, 1u, __ATOMIC_RELAXED, __HIP_MEMORY_SCOPE_AGENT);
            if (so == target * 8 - 1) {
                __hip_atomic_store(gen, target, __ATOMIC_RELAXED, __HIP_MEMORY_SCOPE_AGENT);
                released = true;
            }
        }
        if (!released) {
            while (__hip_atomic_load(gen, __ATOMIC_RELAXED, __HIP_MEMORY_SCOPE_AGENT) < target)
                __builtin_amdgcn_s_sleep(2);
        }
    }
    __syncthreads();
}

__global__ void wat_init(const float* __restrict__ Wa, u16* __restrict__ WaT) {
    for (int idx = blockIdx.x * 256 + threadIdx.x; idx < 32 * 512; idx += gridDim.x * 256) {
        const int n = idx >> 9, k = idx & 511;
        WaT[idx] = (n < 30) ? f2bf(Wa[k * 30 + n]) : (u16)0;
    }
}

__global__ __launch_bounds__(256, 1) void hw_main(
    const float* __restrict__ stroke, const float* __restrict__ charseq, const float* __restrict__ kappa0,
    const float* __restrict__ W0, const float* __restrict__ U0, const float* __restrict__ b0,
    const float* __restrict__ W1, const float* __restrict__ U1, const float* __restrict__ b1,
    const float* __restrict__ W2, const float* __restrict__ U2, const float* __restrict__ b2,
    const float* __restrict__ ba, const float* __restrict__ Wm, const float* __restrict__ bm,
    float* __restrict__ out, char* __restrict__ ws)
{
    __shared__ __align__(16) char smem[55296];
    u32* ctrl = (u32*)ws;
    u16* augr  = (u16*)(ws + AUGR_OFF);
    u16* aug2r = (u16*)(ws + AUG2R_OFF);
    const u16* WaT = (const u16*)(ws + WAT_OFF);

    const int blk = blockIdx.x, tid = threadIdx.x;
    const int wave = tid >> 6, lane = tid & 63;
    const int quad = lane >> 4, l15 = lane & 15;

    if (blk < 32) {
        // ---------------- Stage S0: lstm0, step t=i.  WG owns all 64 batches x 16 h-cols.
        const int s = blk;
        float* w0s = (float*)smem;        // 3*64
        float* b0s = (float*)smem + 192;  // 64
        float* zb  = (float*)smem + 256;  // 4*64*17
        if (tid < 192) { int d = tid >> 6, c = tid & 63; int cn = (c >> 4) * 512 + s * 16 + (c & 15);
            w0s[d * 64 + c] = W0[d * 2048 + cn]; }
        if (tid < 64) { int c = tid; int cn = (c >> 4) * 512 + s * 16 + (c & 15); b0s[c] = b0[cn]; }
        v8s bw[16];
        {
            const int cn = (l15 >> 2) * 512 + s * 16 + wave * 4 + (l15 & 3);
            #pragma unroll
            for (int kc = 0; kc < 16; kc++)
                #pragma unroll
                for (int j = 0; j < 8; j++)
                    bw[kc][j] = f2bfs(U0[(kc * 32 + quad * 8 + j) * 2048 + cn]);
        }
        float cst[4] = {0.f, 0.f, 0.f, 0.f};
        float* zw = zb + wave * (64 * 17);
        __syncthreads();
        #pragma unroll 1
        for (int i = 0; i <= TT + 3; i++) {
            if (i < TT) {
                const int t = i;
                const u16* Ap = augr + ((size_t)((t + 3) & 3)) * BB * AUGW;
                v4f a0 = {0.f,0.f,0.f,0.f}, a1 = {0.f,0.f,0.f,0.f}, a2 = {0.f,0.f,0.f,0.f}, a3 = {0.f,0.f,0.f,0.f};
                const int kqo = quad * 8;
                #pragma unroll
                for (int kc = 0; kc < 16; kc++) {
                    const int col = kc * 32 + kqo;
                    v8s x0 = ldv8(Ap + (0 * 16 + l15) * AUGW + col);
                    v8s x1 = ldv8(Ap + (1 * 16 + l15) * AUGW + col);
                    v8s x2 = ldv8(Ap + (2 * 16 + l15) * AUGW + col);
                    v8s x3 = ldv8(Ap + (3 * 16 + l15) * AUGW + col);
                    a0 = __builtin_amdgcn_mfma_f32_16x16x32_bf16(x0, bw[kc], a0, 0, 0, 0);
                    a1 = __builtin_amdgcn_mfma_f32_16x16x32_bf16(x1, bw[kc], a1, 0, 0, 0);
                    a2 = __builtin_amdgcn_mfma_f32_16x16x32_bf16(x2, bw[kc], a2, 0, 0, 0);
                    a3 = __builtin_amdgcn_mfma_f32_16x16x32_bf16(x3, bw[kc], a3, 0, 0, 0);
                }
                #pragma unroll
                for (int r = 0; r < 4; r++) {
                    zw[(0 * 16 + quad * 4 + r) * 17 + l15] = a0[r];
                    zw[(1 * 16 + quad * 4 + r) * 17 + l15] = a1[r];
                    zw[(2 * 16 + quad * 4 + r) * 17 + l15] = a2[r];
                    zw[(3 * 16 + quad * 4 + r) * 17 + l15] = a3[r];
                }
                __syncthreads();
                u16* hdst = augr + ((size_t)(t & 3)) * BB * AUGW;
                {
                    const int b = tid & 63, jq = tid >> 6;
                    const float xx0 = stroke[(b * TT + t) * 3 + 0];
                    const float xx1 = stroke[(b * TT + t) * 3 + 1];
                    const float xx2 = stroke[(b * TT + t) * 3 + 2];
                    u16 hv[4];
                    #pragma unroll
                    for (int m = 0; m < 4; m++) {
                        const int j = jq * 4 + m;
                        float z[4];
                        #pragma unroll
                        for (int g = 0; g < 4; g++) {
                            const int c = g * 16 + j;
                            z[g] = zb[jq * (64 * 17) + b * 17 + (g * 4 + m)]
                                 + b0s[c] + xx0 * w0s[c] + xx1 * w0s[64 + c] + xx2 * w0s[128 + c];
                        }
                        const float cc = sigf(z[1]) * cst[m] + sigf(z[0]) * tanhf2(z[2]);
                        cst[m] = cc;
                        hv[m] = f2bf(sigf(z[3]) * tanhf2(cc));
                    }
                    st8(hdst + b * AUGW + s * 16 + jq * 4, hv[0], hv[1], hv[2], hv[3]);
                }
            }
            if (i < TT + 3) gbar(ctrl, (u32)(i + 1));
        }
    } else if (blk < 96) {
        // ---------------- Stage S1: lstm1, step t1=i-2.  32 batches x 16 h-cols per WG.
        const int q = blk - 32, mg = q >> 5, cs = q & 31;
        float* b1s = (float*)smem;
        float* zb  = (float*)smem + 64;   // 4*32*17
        if (tid < 64) { int c = tid; int cn = (c >> 4) * 512 + cs * 16 + (c & 15); b1s[c] = b1[cn]; }
        v8s bw[35];
        {
            const int cn = (l15 >> 2) * 512 + cs * 16 + wave * 4 + (l15 & 3);
            #pragma unroll
            for (int kc = 0; kc < 35; kc++)
                #pragma unroll
                for (int j = 0; j < 8; j++) {
                    const int k = kc * 32 + quad * 8 + j;
                    short v = 0;
                    if (k < 595) v = f2bfs(W1[k * 2048 + cn]);
                    else if (k >= 596 && k < 1108) v = f2bfs(U1[(k - 596) * 2048 + cn]);
                    bw[kc][j] = v;
                }
        }
        float cst[4] = {0.f, 0.f, 0.f, 0.f};
        float* zw = zb + wave * (32 * 17);
        __syncthreads();
        #pragma unroll 1
        for (int i = 0; i <= TT + 3; i++) {
            if (i >= 2 && i <= TT + 1) {
                const int t1 = i - 2;
                const u16* Ap = augr + ((size_t)(t1 & 3)) * BB * AUGW + (size_t)mg * 32 * AUGW;
                v4f a0 = {0.f,0.f,0.f,0.f}, a1 = {0.f,0.f,0.f,0.f};
                const int kqo = quad * 8;
                #pragma unroll
                for (int kc = 0; kc < 35; kc++) {
                    const int col = kc * 32 + kqo;
                    v8s x0 = ldv8(Ap + l15 * AUGW + col);
                    v8s x1 = ldv8(Ap + (16 + l15) * AUGW + col);
                    a0 = __builtin_amdgcn_mfma_f32_16x16x32_bf16(x0, bw[kc], a0, 0, 0, 0);
                    a1 = __builtin_amdgcn_mfma_f32_16x16x32_bf16(x1, bw[kc], a1, 0, 0, 0);
                }
                #pragma unroll
                for (int r = 0; r < 4; r++) {
                    zw[(quad * 4 + r) * 17 + l15] = a0[r];
                    zw[(16 + quad * 4 + r) * 17 + l15] = a1[r];
                }
                __syncthreads();
                u16* h1a = augr + ((size_t)((t1 + 1) & 3)) * BB * AUGW;
                u16* h1b = aug2r + ((size_t)(t1 & 3)) * BB * AUG2W;
                if (tid < 128) {
                    const int bl = tid & 31, jq = tid >> 5;  // jq in 0..3
                    const int b = mg * 32 + bl;
                    u16 hv[4];
                    #pragma unroll
                    for (int m = 0; m < 4; m++) {
                        const int j = jq * 4 + m;
                        float z[4];
                        #pragma unroll
                        for (int g = 0; g < 4; g++)
                            z[g] = zb[jq * (32 * 17) + bl * 17 + (g * 4 + m)] + b1s[g * 16 + j];
                        const float cc = sigf(z[1]) * cst[m] + sigf(z[0]) * tanhf2(z[2]);
                        cst[m] = cc;
                        hv[m] = f2bf(sigf(z[3]) * tanhf2(cc));
                    }
                    st8(h1a + b * AUGW + 596 + cs * 16 + jq * 4, hv[0], hv[1], hv[2], hv[3]);
                    st8(h1b + b * AUG2W + cs * 16 + jq * 4, hv[0], hv[1], hv[2], hv[3]);
                }
            }
            if (i < TT + 3) gbar(ctrl, (u32)(i + 1));
        }
    } else if (blk < 160) {
        // ---------------- Stage S2: lstm2, step t2=i-3.  32 batches x 16 h-cols per WG.
        const int q = blk - 96, mg = q >> 5, cs = q & 31;
        float* b2s = (float*)smem;
        float* zb  = (float*)smem + 64;
        if (tid < 64) { int c = tid; int cn = (c >> 4) * 512 + cs * 16 + (c & 15); b2s[c] = b2[cn]; }
        v8s bw[32];
        {
            const int cn = (l15 >> 2) * 512 + cs * 16 + wave * 4 + (l15 & 3);
            #pragma unroll
            for (int kc = 0; kc < 32; kc++)
                #pragma unroll
                for (int j = 0; j < 8; j++) {
                    const int k = kc * 32 + quad * 8 + j;
                    bw[kc][j] = (k < 512) ? f2bfs(W2[k * 2048 + cn]) : f2bfs(U2[(k - 512) * 2048 + cn]);
                }
        }
        float cst[4] = {0.f, 0.f, 0.f, 0.f};
        float* zw = zb + wave * (32 * 17);
        __syncthreads();
        #pragma unroll 1
        for (int i = 0; i <= TT + 3; i++) {
            if (i >= 3 && i <= TT + 2) {
                const int t2 = i - 3;
                const u16* Ap = aug2r + ((size_t)(t2 & 3)) * BB * AUG2W + (size_t)mg * 32 * AUG2W;
                v4f a0 = {0.f,0.f,0.f,0.f}, a1 = {0.f,0.f,0.f,0.f};
                const int kqo = quad * 8;
                #pragma unroll
                for (int kc = 0; kc < 32; kc++) {
                    const int col = kc * 32 + kqo;
                    v8s x0 = ldv8(Ap + l15 * AUG2W + col);
                    v8s x1 = ldv8(Ap + (16 + l15) * AUG2W + col);
                    a0 = __builtin_amdgcn_mfma_f32_16x16x32_bf16(x0, bw[kc], a0, 0, 0, 0);
                    a1 = __builtin_amdgcn_mfma_f32_16x16x32_bf16(x1, bw[kc], a1, 0, 0, 0);
                }
                #pragma unroll
                for (int r = 0; r < 4; r++) {
                    zw[(quad * 4 + r) * 17 + l15] = a0[r];
                    zw[(16 + quad * 4 + r) * 17 + l15] = a1[r];
                }
                __syncthreads();
                u16* h2d = aug2r + ((size_t)((t2 + 1) & 3)) * BB * AUG2W;
                if (tid < 128) {
                    const int bl = tid & 31, jq = tid >> 5;
                    const int b = mg * 32 + bl;
                    u16 hv[4];
                    #pragma unroll
                    for (int m = 0; m < 4; m++) {
                        const int j = jq * 4 + m;
                        float z[4];
                        #pragma unroll
                        for (int g = 0; g < 4; g++)
                            z[g] = zb[jq * (32 * 17) + bl * 17 + (g * 4 + m)] + b2s[g * 16 + j];
                        const float cc = sigf(z[1]) * cst[m] + sigf(z[0]) * tanhf2(z[2]);
                        cst[m] = cc;
                        hv[m] = f2bf(sigf(z[3]) * tanhf2(cc));
                    }
                    st8(h2d + b * AUG2W + 512 + cs * 16 + jq * 4, hv[0], hv[1], hv[2], hv[3]);
                }
            }
            if (i < TT + 3) gbar(ctrl, (u32)(i + 1));
        }
    } else if (blk < 176) {
        // ---------------- Stage SA: attention window, step ta=i-1. One batch per wave.
        const int a = blk - 160;
        const int b = a * 4 + wave;
        u16* csb = (u16*)smem;                   // 4*6400 u16
        float* phis = (float*)(smem + 51200);    // 4*80 floats
        #pragma unroll 1
        for (int r = 0; r < 100; r++) { const int idx = r * 64 + lane; csb[wave * 6400 + idx] = f2bf(charseq[b * 6400 + idx]); }
        float kap = (lane < 10) ? kappa0[b * 10 + lane] : 0.f;
        const float baf = (lane < 30) ? ba[lane] : 0.f;
        const int nn = lane & 31;
        const int k0 = (lane >> 5) * 256;
        const u16* wrow = WaT + nn * 512 + k0;
        __syncthreads();
        #pragma unroll 1
        for (int i = 0; i <= TT + 3; i++) {
            if (i >= 1 && i <= TT) {
                const int ta = i - 1;
                const u16* h0p = augr + ((size_t)(ta & 3)) * BB * AUGW + b * AUGW;
                float acc = 0.f;
                #pragma unroll
                for (int kk = 0; kk < 32; kk++) {
                    v8s hv = ldv8(h0p + k0 + kk * 8);
                    v8s wv = *(const v8s*)(wrow + kk * 8);
                    #pragma unroll
                    for (int e = 0; e < 8; e++) acc += bf2f((u16)hv[e]) * bf2f((u16)wv[e]);
                }
                acc += __shfl_xor(acc, 32);
                const float abk = __expf(acc + baf);
                const float kofv = __shfl(abk, 20 + (lane < 10 ? lane : 0));
                if (lane < 10) kap += kofv;
                const float u1f = (float)lane, u2f = (float)(64 + lane);
                float p1 = 0.f, p2 = 0.f;
                #pragma unroll
                for (int kk = 0; kk < 10; kk++) {
                    const float al = __shfl(abk, kk);
                    const float be = __shfl(abk, 10 + kk);
                    const float kp = __shfl(kap, kk);
                    const float d1 = kp - u1f, d2 = kp - u2f;
                    p1 += al * __expf(-be * d1 * d1);
                    p2 += al * __expf(-be * d2 * d2);
                }
                phis[wave * 80 + lane] = p1;
                if (lane < 16) phis[wave * 80 + 64 + lane] = p2;
                __syncthreads();
                u16* dst = augr + ((size_t)(ta & 3)) * BB * AUGW + b * AUGW + 512;
                if (lane < 40) {
                    const int c0 = 2 * lane;
                    float w0 = 0.f, w1 = 0.f;
                    #pragma unroll 1
                    for (int u = 0; u < 80; u++) {
                        const float pv = phis[wave * 80 + u];
                        w0 += pv * bf2f(csb[wave * 6400 + u * 80 + c0]);
                        w1 += pv * bf2f(csb[wave * 6400 + u * 80 + c0 + 1]);
                    }
                    st4(dst + c0, f2bf(w0), f2bf(w1));
                } else if (lane == 40) {
                    st4(dst + 80, f2bf(stroke[(b * TT + ta) * 3 + 0]), f2bf(stroke[(b * TT + ta) * 3 + 1]));
                } else if (lane == 41) {
                    st4(dst + 82, f2bf(stroke[(b * TT + ta) * 3 + 2]), (u16)0);
                }
            }
            if (i < TT + 3) gbar(ctrl, (u32)(i + 1));
        }
    } else if (blk < 178) {
        // ---------------- Stage SM: MDN head, step tm=i-4. WG covers 64 batches x 64 N-cols.
        const int wgN = blk - 176;
        float* zb = (float*)smem; // 64*65
        v8s bw[16];
        {
            const int n = wgN * 64 + wave * 16 + l15;
            #pragma unroll
            for (int kc = 0; kc < 16; kc++)
                #pragma unroll
                for (int j = 0; j < 8; j++) {
                    const int k = kc * 32 + quad * 8 + j;
                    bw[kc][j] = (n < 121) ? f2bfs(Wm[k * 121 + n]) : (short)0;
                }
        }
        #pragma unroll 1
        for (int i = 0; i <= TT + 3; i++) {
            if (i >= 4) {
                const int tm = i - 4;
                const u16* Ap = aug2r + ((size_t)((tm + 1) & 3)) * BB * AUG2W + 512;
                v4f a0 = {0.f,0.f,0.f,0.f}, a1 = {0.f,0.f,0.f,0.f}, a2 = {0.f,0.f,0.f,0.f}, a3 = {0.f,0.f,0.f,0.f};
                const int kqo = quad * 8;
                #pragma unroll
                for (int kc = 0; kc < 16; kc++) {
                    const int col = kc * 32 + kqo;
                    v8s x0 = ldv8(Ap + (0 * 16 + l15) * AUG2W + col);
                    v8s x1 = ldv8(Ap + (1 * 16 + l15) * AUG2W + col);
                    v8s x2 = ldv8(Ap + (2 * 16 + l15) * AUG2W + col);
                    v8s x3 = ldv8(Ap + (3 * 16 + l15) * AUG2W + col);
                    a0 = __builtin_amdgcn_mfma_f32_16x16x32_bf16(x0, bw[kc], a0, 0, 0, 0);
                    a1 = __builtin_amdgcn_mfma_f32_16x16x32_bf16(x1, bw[kc], a1, 0, 0, 0);
                    a2 = __builtin_amdgcn_mfma_f32_16x16x32_bf16(x2, bw[kc], a2, 0, 0, 0);
                    a3 = __builtin_amdgcn_mfma_f32_16x16x32_bf16(x3, bw[kc], a3, 0, 0, 0);
                }
                #pragma unroll
                for (int r = 0; r < 4; r++) {
                    zb[(0 * 16 + quad * 4 + r) * 65 + wave * 16 + l15] = a0[r];
                    zb[(1 * 16 + quad * 4 + r) * 65 + wave * 16 + l15] = a1[r];
                    zb[(2 * 16 + quad * 4 + r) * 65 + wave * 16 + l15] = a2[r];
                    zb[(3 * 16 + quad * 4 + r) * 65 + wave * 16 + l15] = a3[r];
                }
                __syncthreads();
                if (tid < 64) {
                    const int b = tid;
                    float* zr = zb + b * 65;
                    float* orow = out + ((size_t)(b * TT + tm)) * 121;
                    if (wgN == 0) {
                        #pragma unroll 1
                        for (int nl = 0; nl < 64; nl++) zr[nl] += bm[nl];
                        float mx = -1e30f;
                        #pragma unroll 1
                        for (int nl = 1; nl <= 20; nl++) mx = fmaxf(mx, zr[nl]);
                        float ss = 0.f;
                        #pragma unroll 1
                        for (int nl = 1; nl <= 20; nl++) { const float e = __expf(zr[nl] - mx); zr[nl] = e; ss += e; }
                        const float inv = 1.f / ss;
                        orow[0] = sigf(-zr[0]);
                        #pragma unroll 1
                        for (int nl = 1; nl <= 20; nl++) orow[nl] = zr[nl] * inv;
                        #pragma unroll 1
                        for (int nl = 21; nl <= 60; nl++) orow[nl] = zr[nl];
                        #pragma unroll 1
                        for (int nl = 61; nl < 64; nl++) orow[nl] = __expf(zr[nl]);
                    } else {
                        #pragma unroll 1
                        for (int nl = 0; nl < 57; nl++) {
                            const int n = 64 + nl;
                            const float z = zr[nl] + bm[n];
                            orow[n] = (n <= 100) ? __expf(z) : tanhf2(z);
                        }
                    }
                }
            }
            if (i < TT + 3) gbar(ctrl, (u32)(i + 1));
        }
    } else {
        // ---------------- idle blocks: participate in barriers only
        #pragma unroll 1
        for (int i = 0; i <= TT + 3; i++)
            if (i < TT + 3) gbar(ctrl, (u32)(i + 1));
    }
}

extern "C" void kernel_launch(void* const* d_in, const int* in_sizes, int n_in,
                              void* d_out, int out_size, void* d_ws, size_t ws_size,
                              hipStream_t stream) {
    const float* stroke  = (const float*)d_in[0];
    const float* charseq = (const float*)d_in[1];
    const float* kappa0  = (const float*)d_in[2];
    const float* W0 = (const float*)d_in[3];
    const float* U0 = (const float*)d_in[4];
    const float* b0 = (const float*)d_in[5];
    const float* W1 = (const float*)d_in[6];
    const float* U1 = (const float*)d_in[7];
    const float* b1 = (const float*)d_in[8];
    const float* W2 = (const float*)d_in[9];
    const float* U2 = (const float*)d_in[10];
    const float* b2 = (const float*)d_in[11];
    const float* Wa = (const float*)d_in[12];
    const float* ba = (const float*)d_in[13];
    const float* Wm = (const float*)d_in[14];
    const float* bm = (const float*)d_in[15];
    char* ws = (char*)d_ws;

    hipMemsetAsync(d_ws, 0, WS_ZERO, stream);
    wat_init<<<8, 256, 0, stream>>>(Wa, (u16*)(ws + WAT_OFF));
    hw_main<<<NBLK, 256, 0, stream>>>(stroke, charseq, kappa0, W0, U0, b0,
                                      W1, U1, b1, W2, U2, b2, ba, Wm, bm,
                                      (float*)d_out, ws);
}

// Round 4
// 10688.798 us; speedup vs baseline: 1.6647x; 1.5748x over previous
//
#include <hip/hip_runtime.h>

typedef unsigned short u16;
typedef unsigned int u32;
typedef unsigned long long u64;
typedef short v8s __attribute__((ext_vector_type(8)));
typedef float v4f __attribute__((ext_vector_type(4)));
typedef unsigned int v4u __attribute__((ext_vector_type(4)));
typedef unsigned int v2u __attribute__((ext_vector_type(2)));

constexpr int BB = 64;      // batch
constexpr int TT = 800;     // timesteps
constexpr int AUGW = 1120;  // [h0(512) | win(80) | stroke(3) | zero-pad(1) | h1prev(596..1107) | pad]
constexpr int AUG2W = 1024; // [h1(512) | h2prev(512)]
constexpr int NBLK = 184;
constexpr int GRP = 23;     // NBLK/8

constexpr size_t AUGR_OFF  = 8192;   // ctrl region below (group cnts / sup / 8 gen flags, 256B-spaced)
constexpr size_t AUG2R_OFF = AUGR_OFF + (size_t)4 * BB * AUGW * 2;
constexpr size_t WAT_OFF   = AUG2R_OFF + (size_t)4 * BB * AUG2W * 2;
constexpr size_t WS_ZERO   = WAT_OFF + (size_t)32 * 512 * 2;

__device__ __forceinline__ float bf2f(u16 u) { return __uint_as_float(((u32)u) << 16); }
__device__ __forceinline__ u16 f2bf(float f) {
    u32 x = __float_as_uint(f);
    return (u16)((x + 0x7fffu + ((x >> 16) & 1u)) >> 16);
}
__device__ __forceinline__ short f2bfs(float f) { return (short)f2bf(f); }
__device__ __forceinline__ float sigf(float x) { return 1.f / (1.f + __expf(-x)); }
__device__ __forceinline__ float tanhf2(float x) { return 1.f - 2.f / (1.f + __expf(2.f * x)); }

// ---- coherent ring access: plain buffer ops with cpol = SC0|SC1 (bypass stale L1/L2,
// served at MALL = agent coherence point), fully pipelined by normal vmcnt scheduling.
__device__ __forceinline__ __amdgpu_buffer_rsrc_t mkrsrc(const void* p) {
    return __builtin_amdgcn_make_buffer_rsrc((void*)p, (short)0, -1, 0x00020000);
}
__device__ __forceinline__ v8s ldq(__amdgpu_buffer_rsrc_t r, int off) {
    v4u t = __builtin_amdgcn_raw_buffer_load_b128(r, off, 0, 17);
    v8s x; __builtin_memcpy(&x, &t, 16); return x;
}
__device__ __forceinline__ void stq8(__amdgpu_buffer_rsrc_t r, int off, u16 a, u16 b, u16 c, u16 d) {
    v2u t; t[0] = (u32)a | ((u32)b << 16); t[1] = (u32)c | ((u32)d << 16);
    __builtin_amdgcn_raw_buffer_store_b64(t, r, off, 0, 17);
}
__device__ __forceinline__ void stq4(__amdgpu_buffer_rsrc_t r, int off, u16 a, u16 b) {
    u32 t = (u32)a | ((u32)b << 16);
    __builtin_amdgcn_raw_buffer_store_b32(t, r, off, 0, 17);
}

// two-level grid barrier, relaxed monotone counters, DISTRIBUTED release flags:
// 8 gen flags in separate 256B-spaced lines, <=23 spinners each, s_sleep(8) backoff.
__device__ __forceinline__ void gbar(u32* ctrl, u32 target) {
    __syncthreads();
    if (threadIdx.x == 0) {
        const int g = blockIdx.x & 7;
        u32* cnt = ctrl + g * 64;          // bytes g*256
        u32* sup = ctrl + 512;             // byte 2048
        u32* gen = ctrl + 576 + g * 64;    // bytes 2304 + g*256
        bool released = false;
        u32 old = __hip_atomic_fetch_add(cnt, 1u, __ATOMIC_RELAXED, __HIP_MEMORY_SCOPE_AGENT);
        if (old == target * GRP - 1) {
            u32 so = __hip_atomic_fetch_add(sup, 1u, __ATOMIC_RELAXED, __HIP_MEMORY_SCOPE_AGENT);
            if (so == target * 8 - 1) {
                #pragma unroll
                for (int k = 0; k < 8; k++)
                    __hip_atomic_store(ctrl + 576 + k * 64, target, __ATOMIC_RELAXED, __HIP_MEMORY_SCOPE_AGENT);
                released = true;
            }
        }
        if (!released) {
            while (__hip_atomic_load(gen, __ATOMIC_RELAXED, __HIP_MEMORY_SCOPE_AGENT) < target)
                __builtin_amdgcn_s_sleep(8);
        }
    }
    __syncthreads();
}

__global__ void wat_init(const float* __restrict__ Wa, u16* __restrict__ WaT) {
    for (int idx = blockIdx.x * 256 + threadIdx.x; idx < 32 * 512; idx += gridDim.x * 256) {
        const int n = idx >> 9, k = idx & 511;
        WaT[idx] = (n < 30) ? f2bf(Wa[k * 30 + n]) : (u16)0;
    }
}

__global__ __launch_bounds__(256, 1) void hw_main(
    const float* __restrict__ stroke, const float* __restrict__ charseq, const float* __restrict__ kappa0,
    const float* __restrict__ W0, const float* __restrict__ U0, const float* __restrict__ b0,
    const float* __restrict__ W1, const float* __restrict__ U1, const float* __restrict__ b1,
    const float* __restrict__ W2, const float* __restrict__ U2, const float* __restrict__ b2,
    const float* __restrict__ ba, const float* __restrict__ Wm, const float* __restrict__ bm,
    float* __restrict__ out, char* __restrict__ ws)
{
    __shared__ __align__(16) char smem[55296];
    u32* ctrl = (u32*)ws;
    u16* augr  = (u16*)(ws + AUGR_OFF);
    u16* aug2r = (u16*)(ws + AUG2R_OFF);
    const u16* WaT = (const u16*)(ws + WAT_OFF);

    const int blk = blockIdx.x, tid = threadIdx.x;
    const int wave = tid >> 6, lane = tid & 63;
    const int quad = lane >> 4, l15 = lane & 15;

    if (blk < 32) {
        // ---------------- Stage S0: lstm0, step t=i.  WG owns all 64 batches x 16 h-cols.
        const int s = blk;
        __amdgpu_buffer_rsrc_t ra = mkrsrc(augr);
        float* w0s = (float*)smem;        // 3*64
        float* b0s = (float*)smem + 192;  // 64
        float* zb  = (float*)smem + 256;  // 4*64*17
        if (tid < 192) { int d = tid >> 6, c = tid & 63; int cn = (c >> 4) * 512 + s * 16 + (c & 15);
            w0s[d * 64 + c] = W0[d * 2048 + cn]; }
        if (tid < 64) { int c = tid; int cn = (c >> 4) * 512 + s * 16 + (c & 15); b0s[c] = b0[cn]; }
        v8s bw[16];
        {
            const int cn = (l15 >> 2) * 512 + s * 16 + wave * 4 + (l15 & 3);
            #pragma unroll
            for (int kc = 0; kc < 16; kc++)
                #pragma unroll
                for (int j = 0; j < 8; j++)
                    bw[kc][j] = f2bfs(U0[(kc * 32 + quad * 8 + j) * 2048 + cn]);
        }
        float cst[4] = {0.f, 0.f, 0.f, 0.f};
        float* zw = zb + wave * (64 * 17);
        __syncthreads();
        #pragma unroll 1
        for (int i = 0; i <= TT + 3; i++) {
            if (i < TT) {
                const int t = i;
                const int kqo = quad * 8;
                const int sb = ((t + 3) & 3) * BB * AUGW * 2;
                const int ro0 = sb + ((0 * 16 + l15) * AUGW + kqo) * 2;
                const int ro1 = sb + ((1 * 16 + l15) * AUGW + kqo) * 2;
                const int ro2 = sb + ((2 * 16 + l15) * AUGW + kqo) * 2;
                const int ro3 = sb + ((3 * 16 + l15) * AUGW + kqo) * 2;
                v4f a0 = {0.f,0.f,0.f,0.f}, a1 = {0.f,0.f,0.f,0.f}, a2 = {0.f,0.f,0.f,0.f}, a3 = {0.f,0.f,0.f,0.f};
                #pragma unroll
                for (int kc = 0; kc < 16; kc++) {
                    v8s x0 = ldq(ra, ro0 + kc * 64);
                    v8s x1 = ldq(ra, ro1 + kc * 64);
                    v8s x2 = ldq(ra, ro2 + kc * 64);
                    v8s x3 = ldq(ra, ro3 + kc * 64);
                    a0 = __builtin_amdgcn_mfma_f32_16x16x32_bf16(x0, bw[kc], a0, 0, 0, 0);
                    a1 = __builtin_amdgcn_mfma_f32_16x16x32_bf16(x1, bw[kc], a1, 0, 0, 0);
                    a2 = __builtin_amdgcn_mfma_f32_16x16x32_bf16(x2, bw[kc], a2, 0, 0, 0);
                    a3 = __builtin_amdgcn_mfma_f32_16x16x32_bf16(x3, bw[kc], a3, 0, 0, 0);
                }
                #pragma unroll
                for (int r = 0; r < 4; r++) {
                    zw[(0 * 16 + quad * 4 + r) * 17 + l15] = a0[r];
                    zw[(1 * 16 + quad * 4 + r) * 17 + l15] = a1[r];
                    zw[(2 * 16 + quad * 4 + r) * 17 + l15] = a2[r];
                    zw[(3 * 16 + quad * 4 + r) * 17 + l15] = a3[r];
                }
                __syncthreads();
                {
                    const int b = tid & 63, jq = tid >> 6;
                    const float xx0 = stroke[(b * TT + t) * 3 + 0];
                    const float xx1 = stroke[(b * TT + t) * 3 + 1];
                    const float xx2 = stroke[(b * TT + t) * 3 + 2];
                    u16 hv[4];
                    #pragma unroll
                    for (int m = 0; m < 4; m++) {
                        const int j = jq * 4 + m;
                        float z[4];
                        #pragma unroll
                        for (int g = 0; g < 4; g++) {
                            const int c = g * 16 + j;
                            z[g] = zb[jq * (64 * 17) + b * 17 + (g * 4 + m)]
                                 + b0s[c] + xx0 * w0s[c] + xx1 * w0s[64 + c] + xx2 * w0s[128 + c];
                        }
                        const float cc = sigf(z[1]) * cst[m] + sigf(z[0]) * tanhf2(z[2]);
                        cst[m] = cc;
                        hv[m] = f2bf(sigf(z[3]) * tanhf2(cc));
                    }
                    stq8(ra, ((t & 3) * BB + b) * AUGW * 2 + (s * 16 + jq * 4) * 2,
                         hv[0], hv[1], hv[2], hv[3]);
                }
            }
            if (i < TT + 3) gbar(ctrl, (u32)(i + 1));
        }
    } else if (blk < 96) {
        // ---------------- Stage S1: lstm1, step t1=i-2.  32 batches x 16 h-cols per WG.
        const int q = blk - 32, mg = q >> 5, cs = q & 31;
        __amdgpu_buffer_rsrc_t ra = mkrsrc(augr);
        __amdgpu_buffer_rsrc_t r2 = mkrsrc(aug2r);
        float* b1s = (float*)smem;
        float* zb  = (float*)smem + 64;   // 4*32*17
        if (tid < 64) { int c = tid; int cn = (c >> 4) * 512 + cs * 16 + (c & 15); b1s[c] = b1[cn]; }
        v8s bw[35];
        {
            const int cn = (l15 >> 2) * 512 + cs * 16 + wave * 4 + (l15 & 3);
            #pragma unroll
            for (int kc = 0; kc < 35; kc++)
                #pragma unroll
                for (int j = 0; j < 8; j++) {
                    const int k = kc * 32 + quad * 8 + j;
                    short v = 0;
                    if (k < 595) v = f2bfs(W1[k * 2048 + cn]);
                    else if (k >= 596 && k < 1108) v = f2bfs(U1[(k - 596) * 2048 + cn]);
                    bw[kc][j] = v;
                }
        }
        float cst[4] = {0.f, 0.f, 0.f, 0.f};
        float* zw = zb + wave * (32 * 17);
        __syncthreads();
        #pragma unroll 1
        for (int i = 0; i <= TT + 3; i++) {
            if (i >= 2 && i <= TT + 1) {
                const int t1 = i - 2;
                const int kqo = quad * 8;
                const int sb = ((t1 & 3) * BB + mg * 32) * AUGW * 2;
                const int ro0 = sb + (l15 * AUGW + kqo) * 2;
                const int ro1 = sb + ((16 + l15) * AUGW + kqo) * 2;
                v4f a0 = {0.f,0.f,0.f,0.f}, a1 = {0.f,0.f,0.f,0.f};
                #pragma unroll
                for (int kc = 0; kc < 35; kc++) {
                    v8s x0 = ldq(ra, ro0 + kc * 64);
                    v8s x1 = ldq(ra, ro1 + kc * 64);
                    a0 = __builtin_amdgcn_mfma_f32_16x16x32_bf16(x0, bw[kc], a0, 0, 0, 0);
                    a1 = __builtin_amdgcn_mfma_f32_16x16x32_bf16(x1, bw[kc], a1, 0, 0, 0);
                }
                #pragma unroll
                for (int r = 0; r < 4; r++) {
                    zw[(quad * 4 + r) * 17 + l15] = a0[r];
                    zw[(16 + quad * 4 + r) * 17 + l15] = a1[r];
                }
                __syncthreads();
                if (tid < 128) {
                    const int bl = tid & 31, jq = tid >> 5;  // jq in 0..3
                    const int b = mg * 32 + bl;
                    u16 hv[4];
                    #pragma unroll
                    for (int m = 0; m < 4; m++) {
                        const int j = jq * 4 + m;
                        float z[4];
                        #pragma unroll
                        for (int g = 0; g < 4; g++)
                            z[g] = zb[jq * (32 * 17) + bl * 17 + (g * 4 + m)] + b1s[g * 16 + j];
                        const float cc = sigf(z[1]) * cst[m] + sigf(z[0]) * tanhf2(z[2]);
                        cst[m] = cc;
                        hv[m] = f2bf(sigf(z[3]) * tanhf2(cc));
                    }
                    stq8(ra, (((t1 + 1) & 3) * BB + b) * AUGW * 2 + (596 + cs * 16 + jq * 4) * 2,
                         hv[0], hv[1], hv[2], hv[3]);
                    stq8(r2, ((t1 & 3) * BB + b) * AUG2W * 2 + (cs * 16 + jq * 4) * 2,
                         hv[0], hv[1], hv[2], hv[3]);
                }
            }
            if (i < TT + 3) gbar(ctrl, (u32)(i + 1));
        }
    } else if (blk < 160) {
        // ---------------- Stage S2: lstm2, step t2=i-3.  32 batches x 16 h-cols per WG.
        const int q = blk - 96, mg = q >> 5, cs = q & 31;
        __amdgpu_buffer_rsrc_t r2 = mkrsrc(aug2r);
        float* b2s = (float*)smem;
        float* zb  = (float*)smem + 64;
        if (tid < 64) { int c = tid; int cn = (c >> 4) * 512 + cs * 16 + (c & 15); b2s[c] = b2[cn]; }
        v8s bw[32];
        {
            const int cn = (l15 >> 2) * 512 + cs * 16 + wave * 4 + (l15 & 3);
            #pragma unroll
            for (int kc = 0; kc < 32; kc++)
                #pragma unroll
                for (int j = 0; j < 8; j++) {
                    const int k = kc * 32 + quad * 8 + j;
                    bw[kc][j] = (k < 512) ? f2bfs(W2[k * 2048 + cn]) : f2bfs(U2[(k - 512) * 2048 + cn]);
                }
        }
        float cst[4] = {0.f, 0.f, 0.f, 0.f};
        float* zw = zb + wave * (32 * 17);
        __syncthreads();
        #pragma unroll 1
        for (int i = 0; i <= TT + 3; i++) {
            if (i >= 3 && i <= TT + 2) {
                const int t2 = i - 3;
                const int kqo = quad * 8;
                const int sb = ((t2 & 3) * BB + mg * 32) * AUG2W * 2;
                const int ro0 = sb + (l15 * AUG2W + kqo) * 2;
                const int ro1 = sb + ((16 + l15) * AUG2W + kqo) * 2;
                v4f a0 = {0.f,0.f,0.f,0.f}, a1 = {0.f,0.f,0.f,0.f};
                #pragma unroll
                for (int kc = 0; kc < 32; kc++) {
                    v8s x0 = ldq(r2, ro0 + kc * 64);
                    v8s x1 = ldq(r2, ro1 + kc * 64);
                    a0 = __builtin_amdgcn_mfma_f32_16x16x32_bf16(x0, bw[kc], a0, 0, 0, 0);
                    a1 = __builtin_amdgcn_mfma_f32_16x16x32_bf16(x1, bw[kc], a1, 0, 0, 0);
                }
                #pragma unroll
                for (int r = 0; r < 4; r++) {
                    zw[(quad * 4 + r) * 17 + l15] = a0[r];
                    zw[(16 + quad * 4 + r) * 17 + l15] = a1[r];
                }
                __syncthreads();
                if (tid < 128) {
                    const int bl = tid & 31, jq = tid >> 5;
                    const int b = mg * 32 + bl;
                    u16 hv[4];
                    #pragma unroll
                    for (int m = 0; m < 4; m++) {
                        const int j = jq * 4 + m;
                        float z[4];
                        #pragma unroll
                        for (int g = 0; g < 4; g++)
                            z[g] = zb[jq * (32 * 17) + bl * 17 + (g * 4 + m)] + b2s[g * 16 + j];
                        const float cc = sigf(z[1]) * cst[m] + sigf(z[0]) * tanhf2(z[2]);
                        cst[m] = cc;
                        hv[m] = f2bf(sigf(z[3]) * tanhf2(cc));
                    }
                    stq8(r2, (((t2 + 1) & 3) * BB + b) * AUG2W * 2 + (512 + cs * 16 + jq * 4) * 2,
                         hv[0], hv[1], hv[2], hv[3]);
                }
            }
            if (i < TT + 3) gbar(ctrl, (u32)(i + 1));
        }
    } else if (blk < 176) {
        // ---------------- Stage SA: attention window, step ta=i-1. One batch per wave.
        const int a = blk - 160;
        const int b = a * 4 + wave;
        __amdgpu_buffer_rsrc_t ra = mkrsrc(augr);
        u16* csb = (u16*)smem;                   // 4*6400 u16
        float* phis = (float*)(smem + 51200);    // 4*80 floats
        #pragma unroll 1
        for (int r = 0; r < 100; r++) { const int idx = r * 64 + lane; csb[wave * 6400 + idx] = f2bf(charseq[b * 6400 + idx]); }
        float kap = (lane < 10) ? kappa0[b * 10 + lane] : 0.f;
        const float baf = (lane < 30) ? ba[lane] : 0.f;
        const int nn = lane & 31;
        const int k0 = (lane >> 5) * 256;
        const u16* wrow = WaT + nn * 512 + k0;
        __syncthreads();
        #pragma unroll 1
        for (int i = 0; i <= TT + 3; i++) {
            if (i >= 1 && i <= TT) {
                const int ta = i - 1;
                const int hb = (((ta & 3) * BB + b) * AUGW + k0) * 2;
                float acc = 0.f;
                #pragma unroll
                for (int kk = 0; kk < 32; kk++) {
                    v8s hv = ldq(ra, hb + kk * 16);
                    v8s wv = *(const v8s*)(wrow + kk * 8);
                    #pragma unroll
                    for (int e = 0; e < 8; e++) acc += bf2f((u16)hv[e]) * bf2f((u16)wv[e]);
                }
                acc += __shfl_xor(acc, 32);
                const float abk = __expf(acc + baf);
                const float kofv = __shfl(abk, 20 + (lane < 10 ? lane : 0));
                if (lane < 10) kap += kofv;
                const float u1f = (float)lane, u2f = (float)(64 + lane);
                float p1 = 0.f, p2 = 0.f;
                #pragma unroll
                for (int kk = 0; kk < 10; kk++) {
                    const float al = __shfl(abk, kk);
                    const float be = __shfl(abk, 10 + kk);
                    const float kp = __shfl(kap, kk);
                    const float d1 = kp - u1f, d2 = kp - u2f;
                    p1 += al * __expf(-be * d1 * d1);
                    p2 += al * __expf(-be * d2 * d2);
                }
                phis[wave * 80 + lane] = p1;
                if (lane < 16) phis[wave * 80 + 64 + lane] = p2;
                __syncthreads();
                const int db = (((ta & 3) * BB + b) * AUGW + 512) * 2;
                if (lane < 40) {
                    const int c0 = 2 * lane;
                    float w0 = 0.f, w1 = 0.f;
                    #pragma unroll 1
                    for (int u = 0; u < 80; u++) {
                        const float pv = phis[wave * 80 + u];
                        w0 += pv * bf2f(csb[wave * 6400 + u * 80 + c0]);
                        w1 += pv * bf2f(csb[wave * 6400 + u * 80 + c0 + 1]);
                    }
                    stq4(ra, db + c0 * 2, f2bf(w0), f2bf(w1));
                } else if (lane == 40) {
                    stq4(ra, db + 80 * 2, f2bf(stroke[(b * TT + ta) * 3 + 0]), f2bf(stroke[(b * TT + ta) * 3 + 1]));
                } else if (lane == 41) {
                    stq4(ra, db + 82 * 2, f2bf(stroke[(b * TT + ta) * 3 + 2]), (u16)0);
                }
            }
            if (i < TT + 3) gbar(ctrl, (u32)(i + 1));
        }
    } else if (blk < 178) {
        // ---------------- Stage SM: MDN head, step tm=i-4. WG covers 64 batches x 64 N-cols.
        const int wgN = blk - 176;
        __amdgpu_buffer_rsrc_t r2 = mkrsrc(aug2r);
        float* zb = (float*)smem; // 64*65
        v8s bw[16];
        {
            const int n = wgN * 64 + wave * 16 + l15;
            #pragma unroll
            for (int kc = 0; kc < 16; kc++)
                #pragma unroll
                for (int j = 0; j < 8; j++) {
                    const int k = kc * 32 + quad * 8 + j;
                    bw[kc][j] = (n < 121) ? f2bfs(Wm[k * 121 + n]) : (short)0;
                }
        }
        #pragma unroll 1
        for (int i = 0; i <= TT + 3; i++) {
            if (i >= 4) {
                const int tm = i - 4;
                const int kqo = quad * 8;
                const int sb = (((tm + 1) & 3) * BB) * AUG2W * 2 + 512 * 2;
                const int ro0 = sb + ((0 * 16 + l15) * AUG2W + kqo) * 2;
                const int ro1 = sb + ((1 * 16 + l15) * AUG2W + kqo) * 2;
                const int ro2 = sb + ((2 * 16 + l15) * AUG2W + kqo) * 2;
                const int ro3 = sb + ((3 * 16 + l15) * AUG2W + kqo) * 2;
                v4f a0 = {0.f,0.f,0.f,0.f}, a1 = {0.f,0.f,0.f,0.f}, a2 = {0.f,0.f,0.f,0.f}, a3 = {0.f,0.f,0.f,0.f};
                #pragma unroll
                for (int kc = 0; kc < 16; kc++) {
                    v8s x0 = ldq(r2, ro0 + kc * 64);
                    v8s x1 = ldq(r2, ro1 + kc * 64);
                    v8s x2 = ldq(r2, ro2 + kc * 64);
                    v8s x3 = ldq(r2, ro3 + kc * 64);
                    a0 = __builtin_amdgcn_mfma_f32_16x16x32_bf16(x0, bw[kc], a0, 0, 0, 0);
                    a1 = __builtin_amdgcn_mfma_f32_16x16x32_bf16(x1, bw[kc], a1, 0, 0, 0);
                    a2 = __builtin_amdgcn_mfma_f32_16x16x32_bf16(x2, bw[kc], a2, 0, 0, 0);
                    a3 = __builtin_amdgcn_mfma_f32_16x16x32_bf16(x3, bw[kc], a3, 0, 0, 0);
                }
                #pragma unroll
                for (int r = 0; r < 4; r++) {
                    zb[(0 * 16 + quad * 4 + r) * 65 + wave * 16 + l15] = a0[r];
                    zb[(1 * 16 + quad * 4 + r) * 65 + wave * 16 + l15] = a1[r];
                    zb[(2 * 16 + quad * 4 + r) * 65 + wave * 16 + l15] = a2[r];
                    zb[(3 * 16 + quad * 4 + r) * 65 + wave * 16 + l15] = a3[r];
                }
                __syncthreads();
                if (tid < 64) {
                    const int b = tid;
                    float* zr = zb + b * 65;
                    float* orow = out + ((size_t)(b * TT + tm)) * 121;
                    if (wgN == 0) {
                        #pragma unroll 1
                        for (int nl = 0; nl < 64; nl++) zr[nl] += bm[nl];
                        float mx = -1e30f;
                        #pragma unroll 1
                        for (int nl = 1; nl <= 20; nl++) mx = fmaxf(mx, zr[nl]);
                        float ss = 0.f;
                        #pragma unroll 1
                        for (int nl = 1; nl <= 20; nl++) { const float e = __expf(zr[nl] - mx); zr[nl] = e; ss += e; }
                        const float inv = 1.f / ss;
                        orow[0] = sigf(-zr[0]);
                        #pragma unroll 1
                        for (int nl = 1; nl <= 20; nl++) orow[nl] = zr[nl] * inv;
                        #pragma unroll 1
                        for (int nl = 21; nl <= 60; nl++) orow[nl] = zr[nl];
                        #pragma unroll 1
                        for (int nl = 61; nl < 64; nl++) orow[nl] = __expf(zr[nl]);
                    } else {
                        #pragma unroll 1
                        for (int nl = 0; nl < 57; nl++) {
                            const int n = 64 + nl;
                            const float z = zr[nl] + bm[n];
                            orow[n] = (n <= 100) ? __expf(z) : tanhf2(z);
                        }
                    }
                }
            }
            if (i < TT + 3) gbar(ctrl, (u32)(i + 1));
        }
    } else {
        // ---------------- idle blocks: participate in barriers only
        #pragma unroll 1
        for (int i = 0; i <= TT + 3; i++)
            if (i < TT + 3) gbar(ctrl, (u32)(i + 1));
    }
}

extern "C" void kernel_launch(void* const* d_in, const int* in_sizes, int n_in,
                              void* d_out, int out_size, void* d_ws, size_t ws_size,
                              hipStream_t stream) {
    const float* stroke  = (const float*)d_in[0];
    const float* charseq = (const float*)d_in[1];
    const float* kappa0  = (const float*)d_in[2];
    const float* W0 = (const float*)d_in[3];
    const float* U0 = (const float*)d_in[4];
    const float* b0 = (const float*)d_in[5];
    const float* W1 = (const float*)d_in[6];
    const float* U1 = (const float*)d_in[7];
    const float* b1 = (const float*)d_in[8];
    const float* W2 = (const float*)d_in[9];
    const float* U2 = (const float*)d_in[10];
    const float* b2 = (const float*)d_in[11];
    const float* Wa = (const float*)d_in[12];
    const float* ba = (const float*)d_in[13];
    const float* Wm = (const float*)d_in[14];
    const float* bm = (const float*)d_in[15];
    char* ws = (char*)d_ws;

    hipMemsetAsync(d_ws, 0, WS_ZERO, stream);
    wat_init<<<8, 256, 0, stream>>>(Wa, (u16*)(ws + WAT_OFF));
    hw_main<<<NBLK, 256, 0, stream>>>(stroke, charseq, kappa0, W0, U0, b0,
                                      W1, U1, b1, W2, U2, b2, ba, Wm, bm,
                                      (float*)d_out, ws);
}